// Round 6
// baseline (61930.090 us; speedup 1.0000x reference)
//
#include <hip/hip_runtime.h>
#include <cstdint>

// Problem constants (from reference): I=256, H=1024, O=1, T=16384
#define I_DIM   256
#define H_DIM   1024
#define T_STEPS 16384
#define NBLK    128     // persistent blocks, 1 per CU (256 CUs -> 2x residency margin)
#define CELLS   8       // h cells per block  (128*8 = 1024)
#define THREADS 512     // 8 waves; wave wv owns cell wv; 16-lane group = gate

// Fast device math: v_exp_f32 / v_rcp_f32 based, ~1-2 ulp (validated R3-R5:
// absmax vs numpy ref = 0.0 at the harness's print precision).
__device__ __forceinline__ float fast_sigmoid(float x) {
    return __builtin_amdgcn_rcpf(1.f + __expf(-x));
}
__device__ __forceinline__ float fast_tanh(float x) {
    const float a = fabsf(x);
    const float e = __expf(-2.f * a);
    const float t = (1.f - e) * __builtin_amdgcn_rcpf(1.f + e);
    return copysignf(t, x);
}

// ---------------------------------------------------------------------------
// Persistent LSTM scan kernel. R5 machinery (validated: fast gates, pinned
// relaxed publish, register weights, in-wave gate gather) with two serial-path
// cuts:
//  * ONE barrier per step: h_cur double-buffered. Proof: a wave pre-barrier-t
//    passed barrier t-1 => all waves finished step t-2's dot => buffer
//    (t-1)&1 (last read at t-2) is reusable; xbuf write sits after barrier-t
//    so it is ordered after all step-(t-1) tail reads.
//  * 2-deep paced poll: two load-pairs in flight, check the older while the
//    newer flies; 64cy s_nop pacing keeps LLC poll traffic bounded. Detection
//    staleness ~latency+100cy instead of ~latency+650/2.
// ---------------------------------------------------------------------------
__launch_bounds__(THREADS, 2)
__global__ void lstm_persist(const float* __restrict__ x,
                             const float* __restrict__ W_ih,
                             const float* __restrict__ W_hh,
                             const float* __restrict__ b_ih,
                             const float* __restrict__ b_hh,
                             unsigned long long* __restrict__ ring)
{
    __shared__ __align__(16) float h_cur[2][H_DIM];
    __shared__ __align__(16) float xbuf[2][I_DIM];

    const int tid = threadIdx.x;
    const int blk = blockIdx.x;
    const int wv  = tid >> 6;           // wave id = cell within block (0..7)
    const int q   = (tid >> 4) & 3;     // 16-lane group = gate (i,f,g,o)
    const int l   = tid & 15;           // lane within group
    const int row_g = q * H_DIM + blk * CELLS + wv;   // global gate row

    // --- W_hh row slice into registers: lane l covers k = jj*64 + l*4
    float4 w4[16];
    {
        const float4* Wrow = reinterpret_cast<const float4*>(W_hh + (size_t)row_g * H_DIM);
        #pragma unroll
        for (int jj = 0; jj < 16; ++jj) w4[jj] = Wrow[jj * 16 + l];
    }
    // --- W_ih row slice: lane l covers k = s*64 + l*4  (conflict-free LDS reads)
    float4 wih4[4];
    {
        const float4* Wrow = reinterpret_cast<const float4*>(W_ih + (size_t)row_g * I_DIM);
        #pragma unroll
        for (int s = 0; s < 4; ++s) wih4[s] = Wrow[s * 16 + l];
    }
    const float bias_r = b_ih[row_g] + b_hh[row_g];

    // --- x_0 into xbuf[0]
    if (tid < 64)
        *reinterpret_cast<float4*>(&xbuf[0][tid * 4]) =
            *reinterpret_cast<const float4*>(x + tid * 4);
    __syncthreads();

    // xg partial for t=0 (bias folded in on lane 0 of each 16-lane group)
    float xg = (l == 0) ? bias_r : 0.f;
    #pragma unroll
    for (int s = 0; s < 4; ++s) {
        const float4 xv = *reinterpret_cast<const float4*>(&xbuf[0][s * 64 + l * 4]);
        xg += wih4[s].x * xv.x + wih4[s].y * xv.y + wih4[s].z * xv.z + wih4[s].w * xv.w;
    }

    // x_1 into xbuf[1]  (consumed by the t=0 tail, written before the loop)
    if (tid < 64)
        *reinterpret_cast<float4*>(&xbuf[1][tid * 4]) =
            *reinterpret_cast<const float4*>(x + I_DIM + tid * 4);
    int   cur     = 1;      // xbuf[cur] holds x_{t+1}
    float c_state = 0.f;    // cell state (replicated across the wave's 64 lanes)

    for (int t = 0; t < T_STEPS; ++t) {
        // (1) prefetch x_{t+2} into registers (off critical path)
        float4 xpre;
        if (tid < 64) {
            const int tt = (t + 2 < T_STEPS) ? t + 2 : T_STEPS - 1;
            xpre = *reinterpret_cast<const float4*>(x + (size_t)tt * I_DIM + tid * 4);
        }
        // (2) obtain h_{t-1}: 2-deep paced poll of own 2 words (tag==t-1 valid)
        float2 hv;
        if (t == 0) {
            hv.x = 0.f; hv.y = 0.f;
        } else {
            const unsigned long long want = (unsigned long long)(t - 1);
            unsigned long long* p = ring + (((t - 1) & 1) ? H_DIM : 0) + 2 * tid;
            unsigned long long a0, b0, a1, b1;
            a0 = __hip_atomic_load(p,     __ATOMIC_RELAXED, __HIP_MEMORY_SCOPE_AGENT);
            b0 = __hip_atomic_load(p + 1, __ATOMIC_RELAXED, __HIP_MEMORY_SCOPE_AGENT);
            a1 = __hip_atomic_load(p,     __ATOMIC_RELAXED, __HIP_MEMORY_SCOPE_AGENT);
            b1 = __hip_atomic_load(p + 1, __ATOMIC_RELAXED, __HIP_MEMORY_SCOPE_AGENT);
            for (;;) {
                if (((a0 >> 32) == want) & ((b0 >> 32) == want)) break;
                a0 = a1; b0 = b1;
                // pace ~64cy: bound LLC poll traffic without sleep quantization
                asm volatile("s_nop 7\n\ts_nop 7\n\ts_nop 7\n\ts_nop 7\n\t"
                             "s_nop 7\n\ts_nop 7\n\ts_nop 7\n\ts_nop 7");
                a1 = __hip_atomic_load(p,     __ATOMIC_RELAXED, __HIP_MEMORY_SCOPE_AGENT);
                b1 = __hip_atomic_load(p + 1, __ATOMIC_RELAXED, __HIP_MEMORY_SCOPE_AGENT);
            }
            hv.x = __uint_as_float((unsigned)a0);
            hv.y = __uint_as_float((unsigned)b0);
        }
        float* hb = h_cur[(t - 1) & 1];   // (-1)&1 == 1 for t=0
        *reinterpret_cast<float2*>(&hb[2 * tid]) = hv;
        __syncthreads();    // the ONLY barrier per step

        // (3) rotate x double-buffer (post-barrier => ordered after all
        //     step-(t-1) tail reads of this buffer)
        if (tid < 64)
            *reinterpret_cast<float4*>(&xbuf[cur ^ 1][tid * 4]) = xpre;

        // (4) recurrent dot: acc = xg_t + W_hh[row,:] . h_{t-1}
        float acc = xg;
        #pragma unroll
        for (int jj = 0; jj < 16; ++jj) {
            const float4 h4 = *reinterpret_cast<const float4*>(&hb[jj * 64 + l * 4]);
            acc += w4[jj].x * h4.x + w4[jj].y * h4.y + w4[jj].z * h4.z + w4[jj].w * h4.w;
        }
        // (5) 16-lane butterfly -> row value uniform in each 16-lane group
        acc += __shfl_xor(acc, 1);
        acc += __shfl_xor(acc, 2);
        acc += __shfl_xor(acc, 4);
        acc += __shfl_xor(acc, 8);
        // (6) gather the 4 gate rows of this wave's cell (in-wave, no barrier)
        const float gi_r = __shfl(acc, 0);
        const float gf_r = __shfl(acc, 16);
        const float gg_r = __shfl(acc, 32);
        const float go_r = __shfl(acc, 48);
        // (7) gate nonlinearities (fast math; redundant on all 64 lanes)
        const float gi = fast_sigmoid(gi_r);
        const float gf = fast_sigmoid(gf_r);
        const float gg = fast_tanh(gg_r);
        const float go = fast_sigmoid(go_r);
        c_state = gf * c_state + gi * gg;
        const float h_new = go * fast_tanh(c_state);
        // (8) publish h_t ASAP (lane 0 of each wave), pinned: nothing below
        //     may be scheduled above this store.
        if ((tid & 63) == 0) {
            const unsigned long long pack =
                ((unsigned long long)t << 32) | (unsigned long long)__float_as_uint(h_new);
            __hip_atomic_store(ring + ((t & 1) ? H_DIM : 0) + blk * CELLS + wv, pack,
                               __ATOMIC_RELAXED, __HIP_MEMORY_SCOPE_AGENT);
        }
        asm volatile("" ::: "memory");

        // (9) off-critical-path: xg for t+1 (overlaps other waves' polls)
        float xg_n = (l == 0) ? bias_r : 0.f;
        #pragma unroll
        for (int s = 0; s < 4; ++s) {
            const float4 xv = *reinterpret_cast<const float4*>(&xbuf[cur][s * 64 + l * 4]);
            xg_n += wih4[s].x * xv.x + wih4[s].y * xv.y + wih4[s].z * xv.z + wih4[s].w * xv.w;
        }
        xg = xg_n;
        cur ^= 1;
    }
}

// ---------------------------------------------------------------------------
// Final FFN: z = relu(h @ W1.T + b1);  partial_b = sum_j z_j * W2_j per block
// ---------------------------------------------------------------------------
__global__ void ffn_kernel(const unsigned long long* __restrict__ ring,
                           const float* __restrict__ W1,
                           const float* __restrict__ b1,
                           const float* __restrict__ W2,
                           float* __restrict__ partials)
{
    __shared__ float psum[8];
    const int tid = threadIdx.x;        // 256
    const int r2  = tid >> 5;           // 0..7
    const int l2  = tid & 31;
    const int j   = blockIdx.x * 8 + r2;
    const unsigned long long* hslot = ring + (((T_STEPS - 1) & 1) ? H_DIM : 0);

    float acc = 0.f;
    #pragma unroll 8
    for (int kk = 0; kk < 32; ++kk) {
        const int   k  = kk * 32 + l2;
        const float hk = __uint_as_float((unsigned)hslot[k]);
        acc += hk * W1[(size_t)j * H_DIM + k];
    }
    acc += __shfl_xor(acc, 1);
    acc += __shfl_xor(acc, 2);
    acc += __shfl_xor(acc, 4);
    acc += __shfl_xor(acc, 8);
    acc += __shfl_xor(acc, 16);
    if (l2 == 0) {
        float z = acc + b1[j];
        z = z > 0.f ? z : 0.f;
        psum[r2] = z * W2[j];
    }
    __syncthreads();
    if (tid == 0) {
        float s = 0.f;
        #pragma unroll
        for (int i = 0; i < 8; ++i) s += psum[i];
        partials[blockIdx.x] = s;
    }
}

__global__ void out_kernel(const float* __restrict__ partials,
                           const float* __restrict__ b2,
                           float* __restrict__ out)
{
    __shared__ float ws2[2];
    const int tid = threadIdx.x;        // 128
    float v = partials[tid];
    v += __shfl_xor(v, 1);
    v += __shfl_xor(v, 2);
    v += __shfl_xor(v, 4);
    v += __shfl_xor(v, 8);
    v += __shfl_xor(v, 16);
    v += __shfl_xor(v, 32);
    if ((tid & 63) == 0) ws2[tid >> 6] = v;
    __syncthreads();
    if (tid == 0) out[0] = ws2[0] + ws2[1] + b2[0];
}

extern "C" void kernel_launch(void* const* d_in, const int* in_sizes, int n_in,
                              void* d_out, int out_size, void* d_ws, size_t ws_size,
                              hipStream_t stream)
{
    const float* x    = (const float*)d_in[0];   // (1,T,I)
    const float* W_ih = (const float*)d_in[1];   // (4H,I)
    const float* W_hh = (const float*)d_in[2];   // (4H,H)
    const float* b_ih = (const float*)d_in[3];   // (4H)
    const float* b_hh = (const float*)d_in[4];   // (4H)
    const float* W1   = (const float*)d_in[5];   // (H,H)
    const float* b1   = (const float*)d_in[6];   // (H)
    const float* W2   = (const float*)d_in[7];   // (1,H)
    const float* b2   = (const float*)d_in[8];   // (1)
    float* out = (float*)d_out;

    unsigned long long* ring = (unsigned long long*)d_ws;         // 2*H u64 = 16 KiB
    const size_t ring_bytes = (size_t)2 * H_DIM * sizeof(unsigned long long);
    float* partials = (float*)((char*)d_ws + ring_bytes);         // 128 f32

    // Poison ring tags so stale tags from a previous replay can never match
    // (tag 0xAAAAAAAA != any step index). Harness also poisons ws to 0xAA.
    hipMemsetAsync(d_ws, 0xAA, ring_bytes, stream);

    lstm_persist<<<NBLK, THREADS, 0, stream>>>(x, W_ih, W_hh, b_ih, b_hh, ring);
    ffn_kernel<<<128, 256, 0, stream>>>(ring, W1, b1, W2, partials);
    out_kernel<<<1, 128, 0, stream>>>(partials, b2, out);
}

// Round 7
// 30090.247 us; speedup vs baseline: 2.0581x; 2.0581x over previous
//
#include <hip/hip_runtime.h>
#include <cstdint>

// Problem constants (from reference): I=256, H=1024, O=1, T=16384
#define I_DIM   256
#define H_DIM   1024
#define T_STEPS 16384
#define NBLK    64      // persistent blocks (R7: halved vs R5's 128)
#define CELLS   16      // h cells per block  (64*16 = 1024)
#define THREADS 1024    // 16 waves; wave wv owns cell wv; 16-lane group = gate

// Fast device math: v_exp_f32 / v_rcp_f32 based, ~1-2 ulp (validated R3-R6:
// absmax vs numpy ref = 0.0 at the harness's print precision).
__device__ __forceinline__ float fast_sigmoid(float x) {
    return __builtin_amdgcn_rcpf(1.f + __expf(-x));
}
__device__ __forceinline__ float fast_tanh(float x) {
    const float a = fabsf(x);
    const float e = __expf(-2.f * a);
    const float t = (1.f - e) * __builtin_amdgcn_rcpf(1.f + e);
    return copysignf(t, x);
}

// ---------------------------------------------------------------------------
// Persistent LSTM scan kernel. Structure == R5 winner (30.2 ms) with ONE
// change: 64 blocks x 1024 threads (16 cells/block), each thread polls
// exactly ONE ring word. Halves poll traffic (512 KB/round) and the
// straggler pool (max over 64 blocks, not 128). Two barriers per step,
// sticky round-trip poll, fast gates, pinned relaxed publish -- all as R5.
// ---------------------------------------------------------------------------
__launch_bounds__(THREADS, 1)
__global__ void lstm_persist(const float* __restrict__ x,
                             const float* __restrict__ W_ih,
                             const float* __restrict__ W_hh,
                             const float* __restrict__ b_ih,
                             const float* __restrict__ b_hh,
                             unsigned long long* __restrict__ ring)
{
    __shared__ __align__(16) float h_cur[H_DIM];
    __shared__ __align__(16) float xbuf[2][I_DIM];

    const int tid = threadIdx.x;
    const int blk = blockIdx.x;
    const int wv  = tid >> 6;           // wave id = cell within block (0..15)
    const int q   = (tid >> 4) & 3;     // 16-lane group = gate (i,f,g,o)
    const int l   = tid & 15;           // lane within group
    const int row_g = q * H_DIM + blk * CELLS + wv;   // global gate row

    // --- W_hh row slice into registers: lane l covers k = jj*64 + l*4
    float4 w4[16];
    {
        const float4* Wrow = reinterpret_cast<const float4*>(W_hh + (size_t)row_g * H_DIM);
        #pragma unroll
        for (int jj = 0; jj < 16; ++jj) w4[jj] = Wrow[jj * 16 + l];
    }
    // --- W_ih row slice: lane l covers k = s*64 + l*4  (conflict-free LDS reads)
    float4 wih4[4];
    {
        const float4* Wrow = reinterpret_cast<const float4*>(W_ih + (size_t)row_g * I_DIM);
        #pragma unroll
        for (int s = 0; s < 4; ++s) wih4[s] = Wrow[s * 16 + l];
    }
    const float bias_r = b_ih[row_g] + b_hh[row_g];

    // --- x_0 into xbuf[0]
    if (tid < 64)
        *reinterpret_cast<float4*>(&xbuf[0][tid * 4]) =
            *reinterpret_cast<const float4*>(x + tid * 4);
    __syncthreads();

    // xg partial for t=0 (bias folded in on lane 0 of each 16-lane group)
    float xg = (l == 0) ? bias_r : 0.f;
    #pragma unroll
    for (int s = 0; s < 4; ++s) {
        const float4 xv = *reinterpret_cast<const float4*>(&xbuf[0][s * 64 + l * 4]);
        xg += wih4[s].x * xv.x + wih4[s].y * xv.y + wih4[s].z * xv.z + wih4[s].w * xv.w;
    }

    // x_1 into xbuf[1]  (read during t=0 tail, after the t=0 barrier -> safe)
    if (tid < 64)
        *reinterpret_cast<float4*>(&xbuf[1][tid * 4]) =
            *reinterpret_cast<const float4*>(x + I_DIM + tid * 4);
    int   cur     = 1;      // xbuf[cur] holds x_{t+1}
    float c_state = 0.f;    // cell state (replicated across the wave's 64 lanes)

    for (int t = 0; t < T_STEPS; ++t) {
        // (1) prefetch x_{t+2} into registers (off critical path)
        float4 xpre;
        if (tid < 64) {
            const int tt = (t + 2 < T_STEPS) ? t + 2 : T_STEPS - 1;
            xpre = *reinterpret_cast<const float4*>(x + (size_t)tt * I_DIM + tid * 4);
        }
        // (2) obtain h_{t-1}: poll own 1 word (tag==t-1 means valid)
        float hval;
        if (t == 0) {
            hval = 0.f;
        } else {
            const unsigned long long want = (unsigned long long)(t - 1);
            unsigned long long* p = ring + (((t - 1) & 1) ? H_DIM : 0) + tid;
            unsigned long long v;
            do {
                v = __hip_atomic_load(p, __ATOMIC_RELAXED, __HIP_MEMORY_SCOPE_AGENT);
            } while ((v >> 32) != want);
            hval = __uint_as_float((unsigned)v);
        }
        h_cur[tid] = hval;
        __syncthreads();

        // (3) recurrent dot: acc = xg_t + W_hh[row,:] . h_{t-1}
        float acc = xg;
        #pragma unroll
        for (int jj = 0; jj < 16; ++jj) {
            const float4 h4 = *reinterpret_cast<const float4*>(&h_cur[jj * 64 + l * 4]);
            acc += w4[jj].x * h4.x + w4[jj].y * h4.y + w4[jj].z * h4.z + w4[jj].w * h4.w;
        }
        // (4) 16-lane butterfly -> row value uniform in each 16-lane group
        acc += __shfl_xor(acc, 1);
        acc += __shfl_xor(acc, 2);
        acc += __shfl_xor(acc, 4);
        acc += __shfl_xor(acc, 8);
        // (5) gather the 4 gate rows of this wave's cell (in-wave, no barrier)
        const float gi_r = __shfl(acc, 0);
        const float gf_r = __shfl(acc, 16);
        const float gg_r = __shfl(acc, 32);
        const float go_r = __shfl(acc, 48);
        // (6) gate nonlinearities (fast math; redundant on all 64 lanes)
        const float gi = fast_sigmoid(gi_r);
        const float gf = fast_sigmoid(gf_r);
        const float gg = fast_tanh(gg_r);
        const float go = fast_sigmoid(go_r);
        c_state = gf * c_state + gi * gg;
        const float h_new = go * fast_tanh(c_state);
        // (7) publish h_t ASAP (lane 0 of each wave), pinned: nothing below
        //     may be scheduled above this store.
        if ((tid & 63) == 0) {
            const unsigned long long pack =
                ((unsigned long long)t << 32) | (unsigned long long)__float_as_uint(h_new);
            __hip_atomic_store(ring + ((t & 1) ? H_DIM : 0) + blk * CELLS + wv, pack,
                               __ATOMIC_RELAXED, __HIP_MEMORY_SCOPE_AGENT);
        }
        asm volatile("" ::: "memory");

        // (8) off-critical-path: xg for t+1, rotate x double-buffer
        float xg_n = (l == 0) ? bias_r : 0.f;
        #pragma unroll
        for (int s = 0; s < 4; ++s) {
            const float4 xv = *reinterpret_cast<const float4*>(&xbuf[cur][s * 64 + l * 4]);
            xg_n += wih4[s].x * xv.x + wih4[s].y * xv.y + wih4[s].z * xv.z + wih4[s].w * xv.w;
        }
        xg = xg_n;
        __syncthreads();   // protects h_cur reuse + xbuf rotation (R5 structure)
        if (tid < 64)
            *reinterpret_cast<float4*>(&xbuf[cur ^ 1][tid * 4]) = xpre;
        cur ^= 1;
    }
}

// ---------------------------------------------------------------------------
// Final FFN: z = relu(h @ W1.T + b1);  partial_b = sum_j z_j * W2_j per block
// ---------------------------------------------------------------------------
__global__ void ffn_kernel(const unsigned long long* __restrict__ ring,
                           const float* __restrict__ W1,
                           const float* __restrict__ b1,
                           const float* __restrict__ W2,
                           float* __restrict__ partials)
{
    __shared__ float psum[8];
    const int tid = threadIdx.x;        // 256
    const int r2  = tid >> 5;           // 0..7
    const int l2  = tid & 31;
    const int j   = blockIdx.x * 8 + r2;
    const unsigned long long* hslot = ring + (((T_STEPS - 1) & 1) ? H_DIM : 0);

    float acc = 0.f;
    #pragma unroll 8
    for (int kk = 0; kk < 32; ++kk) {
        const int   k  = kk * 32 + l2;
        const float hk = __uint_as_float((unsigned)hslot[k]);
        acc += hk * W1[(size_t)j * H_DIM + k];
    }
    acc += __shfl_xor(acc, 1);
    acc += __shfl_xor(acc, 2);
    acc += __shfl_xor(acc, 4);
    acc += __shfl_xor(acc, 8);
    acc += __shfl_xor(acc, 16);
    if (l2 == 0) {
        float z = acc + b1[j];
        z = z > 0.f ? z : 0.f;
        psum[r2] = z * W2[j];
    }
    __syncthreads();
    if (tid == 0) {
        float s = 0.f;
        #pragma unroll
        for (int i = 0; i < 8; ++i) s += psum[i];
        partials[blockIdx.x] = s;
    }
}

__global__ void out_kernel(const float* __restrict__ partials,
                           const float* __restrict__ b2,
                           float* __restrict__ out)
{
    __shared__ float ws2[2];
    const int tid = threadIdx.x;        // 128
    float v = partials[tid];
    v += __shfl_xor(v, 1);
    v += __shfl_xor(v, 2);
    v += __shfl_xor(v, 4);
    v += __shfl_xor(v, 8);
    v += __shfl_xor(v, 16);
    v += __shfl_xor(v, 32);
    if ((tid & 63) == 0) ws2[tid >> 6] = v;
    __syncthreads();
    if (tid == 0) out[0] = ws2[0] + ws2[1] + b2[0];
}

extern "C" void kernel_launch(void* const* d_in, const int* in_sizes, int n_in,
                              void* d_out, int out_size, void* d_ws, size_t ws_size,
                              hipStream_t stream)
{
    const float* x    = (const float*)d_in[0];   // (1,T,I)
    const float* W_ih = (const float*)d_in[1];   // (4H,I)
    const float* W_hh = (const float*)d_in[2];   // (4H,H)
    const float* b_ih = (const float*)d_in[3];   // (4H)
    const float* b_hh = (const float*)d_in[4];   // (4H)
    const float* W1   = (const float*)d_in[5];   // (H,H)
    const float* b1   = (const float*)d_in[6];   // (H)
    const float* W2   = (const float*)d_in[7];   // (1,H)
    const float* b2   = (const float*)d_in[8];   // (1)
    float* out = (float*)d_out;

    unsigned long long* ring = (unsigned long long*)d_ws;         // 2*H u64 = 16 KiB
    const size_t ring_bytes = (size_t)2 * H_DIM * sizeof(unsigned long long);
    float* partials = (float*)((char*)d_ws + ring_bytes);         // 128 f32

    // Poison ring tags so stale tags from a previous replay can never match
    // (tag 0xAAAAAAAA != any step index). Harness also poisons ws to 0xAA.
    hipMemsetAsync(d_ws, 0xAA, ring_bytes, stream);

    lstm_persist<<<NBLK, THREADS, 0, stream>>>(x, W_ih, W_hh, b_ih, b_hh, ring);
    ffn_kernel<<<128, 256, 0, stream>>>(ring, W1, b1, W2, partials);
    out_kernel<<<1, 128, 0, stream>>>(partials, b2, out);
}